// Round 2
// baseline (557.206 us; speedup 1.0000x reference)
//
#include <hip/hip_runtime.h>
#include <hip/hip_bf16.h>

#define SEQ   4096
#define BATCH 32
#define HID   512
#define MTOT  (SEQ * BATCH)   // 131072

typedef float  f32x4  __attribute__((ext_vector_type(4)));
typedef __bf16 bf16x8 __attribute__((ext_vector_type(8)));
typedef unsigned short ushort8v __attribute__((ext_vector_type(8)));
typedef unsigned int u32;

__device__ __forceinline__ unsigned short f2bf(float f) {
    unsigned int u = __builtin_bit_cast(unsigned int, f);
    u = (u + 0x7fffu + ((u >> 16) & 1u)) >> 16;   // RNE
    return (unsigned short)u;
}

__device__ __forceinline__ float tanh_fast(float x) {
    float ax = fabsf(x);
    float e  = __expf(-2.0f * ax);           // in (0,1]
    float t  = (1.0f - e) * __builtin_amdgcn_rcpf(1.0f + e);
    return copysignf(t, x);
}

// async 16B global -> LDS (dest is wave-uniform base + lane*16)
__device__ __forceinline__ void g2l16(const void* g, void* l) {
    __builtin_amdgcn_global_load_lds(
        (const __attribute__((address_space(1))) u32*)g,
        (__attribute__((address_space(3))) u32*)l, 16, 0, 0);
}

// ---- kernel 1a: W fp32 -> bf16 -----------------------------------------
__global__ __launch_bounds__(256) void cvt_w_kernel(const float* __restrict__ W,
                                                    unsigned short* __restrict__ Wb) {
    int i = (blockIdx.x * 256 + threadIdx.x) * 4;
    float4 f = *(const float4*)(W + i);
    ushort4 u;
    u.x = f2bf(f.x); u.y = f2bf(f.y); u.z = f2bf(f.z); u.w = f2bf(f.w);
    *(ushort4*)(Wb + i) = u;
}

// ---- kernel 1b: x fp32 -> bf16 -----------------------------------------
__global__ __launch_bounds__(256) void cvt_x_kernel(const float* __restrict__ x,
                                                    unsigned short* __restrict__ xb) {
    size_t i = ((size_t)blockIdx.x * 256 + threadIdx.x) * 8;
    float4 a0 = *(const float4*)(x + i);
    float4 a1 = *(const float4*)(x + i + 4);
    ushort8v v;
    v[0] = f2bf(a0.x); v[1] = f2bf(a0.y); v[2] = f2bf(a0.z); v[3] = f2bf(a0.w);
    v[4] = f2bf(a1.x); v[5] = f2bf(a1.y); v[6] = f2bf(a1.z); v[7] = f2bf(a1.w);
    *(ushort8v*)(xb + i) = v;
}

// ---- kernel 2: fused GEMM + tanh + ctx-dot -> simsT partials -----------
// y[m,o] = sum_k xb[m,k]*Wb[o,k]; simsT[(nt*2+wn)][b][s] = sum_{o in slice} ctx[o]*tanh(y+bias[o])
__global__ __launch_bounds__(256) void gemm_sim_bf16(
    const unsigned short* __restrict__ xb, const unsigned short* __restrict__ Wb,
    const float* __restrict__ bias, const float* __restrict__ ctx,
    float* __restrict__ simsT)
{
    __shared__ __align__(16) unsigned short As[128 * 64];
    __shared__ __align__(16) unsigned short Bs[128 * 64];

    // XCD-aware swizzle: 4 nt-blocks of one mt land on the same XCD (L2 A-reuse)
    const int L    = blockIdx.x;
    const int xcd  = L & 7;
    const int slot = L >> 3;
    const int nt   = slot & 3;
    const int mt   = xcd * 128 + (slot >> 2);

    const int tid  = threadIdx.x;
    const int lane = tid & 63;
    const int wave = tid >> 6;
    const int wm = wave >> 1, wn = wave & 1;
    const int l15 = lane & 15, q = lane >> 4;

    // staging lane decomposition: lane -> (row-in-8, chunk); chunk XOR-swizzled by row
    const int srow  = lane >> 3;              // 0..7
    const int skoff = ((lane & 7) ^ srow) * 8; // swizzled k-chunk (elems)

    const unsigned short* Abase = xb + (size_t)(mt * 128) * HID;
    const unsigned short* Bbase = Wb + (size_t)(nt * 128) * HID;

    f32x4 acc[4][4] = {};

    for (int kt = 0; kt < HID / 64; ++kt) {
        const int k0 = kt * 64;
        #pragma unroll
        for (int t = 0; t < 4; ++t) {
            const int c = wave * 4 + t;       // chunk of 8 rows
            g2l16(Abase + (size_t)(c * 8 + srow) * HID + k0 + skoff, &As[c * 512]);
            g2l16(Bbase + (size_t)(c * 8 + srow) * HID + k0 + skoff, &Bs[c * 512]);
        }
        __syncthreads();
        #pragma unroll
        for (int kh = 0; kh < 2; ++kh) {
            bf16x8 af[4], bfr[4];
            const int lc = kh * 4 + q;        // logical 16B chunk within row
            #pragma unroll
            for (int mi = 0; mi < 4; ++mi) {
                const int row = wm * 64 + mi * 16 + l15;
                af[mi] = *(const bf16x8*)&As[row * 64 + (lc ^ (row & 7)) * 8];
            }
            #pragma unroll
            for (int ni = 0; ni < 4; ++ni) {
                const int row = wn * 64 + ni * 16 + l15;
                bfr[ni] = *(const bf16x8*)&Bs[row * 64 + (lc ^ (row & 7)) * 8];
            }
            #pragma unroll
            for (int mi = 0; mi < 4; ++mi)
                #pragma unroll
                for (int ni = 0; ni < 4; ++ni)
                    acc[mi][ni] = __builtin_amdgcn_mfma_f32_16x16x32_bf16(
                        af[mi], bfr[ni], acc[mi][ni], 0, 0, 0);
        }
        __syncthreads();
    }

    // epilogue: ctx-weighted tanh partial over this wave's 64 cols
    float ps[16];
    #pragma unroll
    for (int mi = 0; mi < 4; ++mi)
        #pragma unroll
        for (int r = 0; r < 4; ++r) {
            float s = 0.f;
            #pragma unroll
            for (int ni = 0; ni < 4; ++ni) {
                const int o = nt * 128 + wn * 64 + ni * 16 + l15;
                float y = acc[mi][ni][r] + bias[o];
                s += ctx[o] * tanh_fast(y);
            }
            ps[mi * 4 + r] = s;
        }
    #pragma unroll
    for (int off = 1; off < 16; off <<= 1)
        #pragma unroll
        for (int i = 0; i < 16; ++i)
            ps[i] += __shfl_xor(ps[i], off, 64);
    if (l15 == 0) {
        float* dst = simsT + (size_t)(nt * 2 + wn) * MTOT;
        #pragma unroll
        for (int mi = 0; mi < 4; ++mi)
            #pragma unroll
            for (int r = 0; r < 4; ++r) {
                const int m = mt * 128 + wm * 64 + mi * 16 + q * 4 + r;
                dst[(m & 31) * SEQ + (m >> 5)] = ps[mi * 4 + r];  // [b][s]
            }
    }
}

// ---- kernel 2-fallback: inline-convert gemm (used if ws too small) -----
#define LDSP 72
__global__ __launch_bounds__(256) void gemm_sim_f32(
    const float* __restrict__ x, const unsigned short* __restrict__ Wb,
    const float* __restrict__ bias, const float* __restrict__ ctx,
    float* __restrict__ simsT)
{
    __shared__ __align__(16) unsigned short As[128][LDSP];
    __shared__ __align__(16) unsigned short Bs[128][LDSP];

    const int L    = blockIdx.x;
    const int xcd  = L & 7;
    const int slot = L >> 3;
    const int nt   = slot & 3;
    const int mt   = xcd * 128 + (slot >> 2);

    const int tid  = threadIdx.x;
    const int lane = tid & 63;
    const int wave = tid >> 6;
    const int wm = wave >> 1, wn = wave & 1;
    const int l15 = lane & 15, q = lane >> 4;
    const int rbase = tid >> 3;
    const int kc    = (tid & 7) * 8;

    f32x4 acc[4][4] = {};
    for (int kt = 0; kt < HID / 64; ++kt) {
        const int k0 = kt * 64;
        #pragma unroll
        for (int j = 0; j < 4; ++j) {
            const int row = rbase + j * 32;
            const float4* asrc = (const float4*)(x + (size_t)(mt * 128 + row) * HID + k0 + kc);
            float4 a0 = asrc[0];
            float4 a1 = asrc[1];
            uint4 bsrc = *(const uint4*)(Wb + (size_t)(nt * 128 + row) * HID + k0 + kc);
            ushort8v v;
            v[0] = f2bf(a0.x); v[1] = f2bf(a0.y); v[2] = f2bf(a0.z); v[3] = f2bf(a0.w);
            v[4] = f2bf(a1.x); v[5] = f2bf(a1.y); v[6] = f2bf(a1.z); v[7] = f2bf(a1.w);
            *(ushort8v*)&As[row][kc] = v;
            *(uint4*)&Bs[row][kc]    = bsrc;
        }
        __syncthreads();
        #pragma unroll
        for (int kh = 0; kh < 2; ++kh) {
            bf16x8 af[4], bfr[4];
            #pragma unroll
            for (int mi = 0; mi < 4; ++mi)
                af[mi] = *(const bf16x8*)&As[wm * 64 + mi * 16 + l15][kh * 32 + q * 8];
            #pragma unroll
            for (int ni = 0; ni < 4; ++ni)
                bfr[ni] = *(const bf16x8*)&Bs[wn * 64 + ni * 16 + l15][kh * 32 + q * 8];
            #pragma unroll
            for (int mi = 0; mi < 4; ++mi)
                #pragma unroll
                for (int ni = 0; ni < 4; ++ni)
                    acc[mi][ni] = __builtin_amdgcn_mfma_f32_16x16x32_bf16(
                        af[mi], bfr[ni], acc[mi][ni], 0, 0, 0);
        }
        __syncthreads();
    }
    float ps[16];
    #pragma unroll
    for (int mi = 0; mi < 4; ++mi)
        #pragma unroll
        for (int r = 0; r < 4; ++r) {
            float s = 0.f;
            #pragma unroll
            for (int ni = 0; ni < 4; ++ni) {
                const int o = nt * 128 + wn * 64 + ni * 16 + l15;
                s += ctx[o] * tanh_fast(acc[mi][ni][r] + bias[o]);
            }
            ps[mi * 4 + r] = s;
        }
    #pragma unroll
    for (int off = 1; off < 16; off <<= 1)
        #pragma unroll
        for (int i = 0; i < 16; ++i)
            ps[i] += __shfl_xor(ps[i], off, 64);
    if (l15 == 0) {
        float* dst = simsT + (size_t)(nt * 2 + wn) * MTOT;
        #pragma unroll
        for (int mi = 0; mi < 4; ++mi)
            #pragma unroll
            for (int r = 0; r < 4; ++r) {
                const int m = mt * 128 + wm * 64 + mi * 16 + q * 4 + r;
                dst[(m & 31) * SEQ + (m >> 5)] = ps[mi * 4 + r];
            }
    }
}

// ---- kernel 3: softmax over seq, per batch (coalesced, sums 8 partials) -
__global__ __launch_bounds__(256) void softmax_kernel(const float* __restrict__ simsT,
                                                      float* __restrict__ probsT) {
    const int b = blockIdx.x;
    const int tid = threadIdx.x;
    const int lane = tid & 63, wave = tid >> 6;
    __shared__ float red[4];

    float v[16];
    #pragma unroll
    for (int i = 0; i < 16; ++i) {
        const int s = i * 256 + tid;
        float acc = 0.f;
        #pragma unroll
        for (int p = 0; p < 8; ++p)
            acc += simsT[(size_t)p * MTOT + b * SEQ + s];
        v[i] = acc;
    }

    float mx = -INFINITY;
    #pragma unroll
    for (int i = 0; i < 16; ++i) mx = fmaxf(mx, v[i]);
    #pragma unroll
    for (int off = 32; off >= 1; off >>= 1) mx = fmaxf(mx, __shfl_xor(mx, off, 64));
    if (lane == 0) red[wave] = mx;
    __syncthreads();
    mx = fmaxf(fmaxf(red[0], red[1]), fmaxf(red[2], red[3]));
    __syncthreads();

    float sum = 0.f;
    #pragma unroll
    for (int i = 0; i < 16; ++i) { v[i] = __expf(v[i] - mx); sum += v[i]; }
    #pragma unroll
    for (int off = 32; off >= 1; off >>= 1) sum += __shfl_xor(sum, off, 64);
    if (lane == 0) red[wave] = sum;
    __syncthreads();
    const float inv = 1.0f / (red[0] + red[1] + red[2] + red[3]);

    #pragma unroll
    for (int i = 0; i < 16; ++i)
        probsT[b * SEQ + i * 256 + tid] = v[i] * inv;
}

// ---- kernel 4: weighted-sum pooling (float4, fp32 x for accuracy) ------
__global__ __launch_bounds__(128) void attend_kernel(const float* __restrict__ x,
                                                     const float* __restrict__ probsT,
                                                     float* __restrict__ out) {
    const int st  = blockIdx.x;   // 0..31 (seq tile of 128)
    const int b   = blockIdx.y;   // 0..31
    const int tid = threadIdx.x;  // 0..127 -> float4 over HID
    __shared__ float p[128];
    p[tid] = probsT[b * SEQ + st * 128 + tid];
    __syncthreads();
    f32x4 acc = {};
    const f32x4* xp = (const f32x4*)x + ((size_t)st * 128 * BATCH + b) * (HID / 4) + tid;
    #pragma unroll 8
    for (int s = 0; s < 128; ++s)
        acc += p[s] * xp[(size_t)s * (BATCH * HID / 4)];
    float* o = out + b * HID + tid * 4;
    atomicAdd(o + 0, acc[0]);
    atomicAdd(o + 1, acc[1]);
    atomicAdd(o + 2, acc[2]);
    atomicAdd(o + 3, acc[3]);
}

extern "C" void kernel_launch(void* const* d_in, const int* in_sizes, int n_in,
                              void* d_out, int out_size, void* d_ws, size_t ws_size,
                              hipStream_t stream) {
    const float* x    = (const float*)d_in[0];
    const float* W    = (const float*)d_in[1];
    const float* bias = (const float*)d_in[2];
    const float* ctx  = (const float*)d_in[3];
    float* out = (float*)d_out;

    const size_t xb_bytes    = (size_t)MTOT * HID * 2;   // 128 MB
    const size_t wb_bytes    = (size_t)HID * HID * 2;    // 512 KB
    const size_t sims_bytes  = (size_t)8 * MTOT * 4;     // 4 MB
    const size_t probs_bytes = (size_t)MTOT * 4;         // 512 KB
    const bool big = ws_size >= xb_bytes + wb_bytes + sims_bytes + probs_bytes;

    char* w = (char*)d_ws;
    unsigned short* xb = (unsigned short*)w;
    unsigned short* Wb;
    float *simsT, *probsT;
    if (big) {
        Wb     = (unsigned short*)(w + xb_bytes);
        simsT  = (float*)(w + xb_bytes + wb_bytes);
        probsT = (float*)(w + xb_bytes + wb_bytes + sims_bytes);
    } else {
        Wb     = (unsigned short*)w;
        simsT  = (float*)(w + wb_bytes);
        probsT = (float*)(w + wb_bytes + sims_bytes);
    }

    hipMemsetAsync(d_out, 0, (size_t)out_size * sizeof(float), stream);
    cvt_w_kernel<<<HID * HID / 1024, 256, 0, stream>>>(W, Wb);
    if (big) {
        cvt_x_kernel<<<(int)((size_t)MTOT * HID / 2048), 256, 0, stream>>>(x, xb);
        gemm_sim_bf16<<<4096, 256, 0, stream>>>(xb, Wb, bias, ctx, simsT);
    } else {
        gemm_sim_f32<<<4096, 256, 0, stream>>>(x, Wb, bias, ctx, simsT);
    }
    softmax_kernel<<<BATCH, 256, 0, stream>>>(simsT, probsT);
    attend_kernel<<<dim3(32, 32), 128, 0, stream>>>(x, probsT, out);
}

// Round 3
// 496.794 us; speedup vs baseline: 1.1216x; 1.1216x over previous
//
#include <hip/hip_runtime.h>
#include <hip/hip_bf16.h>

#define SEQ   4096
#define BATCH 32
#define HID   512
#define MTOT  (SEQ * BATCH)   // 131072

typedef float  f32x4  __attribute__((ext_vector_type(4)));
typedef float  f32x8  __attribute__((ext_vector_type(8)));
typedef __bf16 bf16x8 __attribute__((ext_vector_type(8)));
typedef unsigned int u32;

__device__ __forceinline__ unsigned short f2bf(float f) {
    unsigned int u = __builtin_bit_cast(unsigned int, f);
    u = (u + 0x7fffu + ((u >> 16) & 1u)) >> 16;   // RNE
    return (unsigned short)u;
}

__device__ __forceinline__ float tanh_fast(float x) {
    float ax = fabsf(x);
    float e  = __expf(-2.0f * ax);           // in (0,1]
    float t  = (1.0f - e) * __builtin_amdgcn_rcpf(1.0f + e);
    return copysignf(t, x);
}

// async 16B global -> LDS (dest is wave-uniform base + lane*16)
__device__ __forceinline__ void g2l16(const void* g, void* l) {
    __builtin_amdgcn_global_load_lds(
        (const __attribute__((address_space(1))) u32*)g,
        (__attribute__((address_space(3))) u32*)l, 16, 0, 0);
}

// ---- kernel 1: W fp32 -> bf16 ------------------------------------------
__global__ __launch_bounds__(256) void cvt_w_kernel(const float* __restrict__ W,
                                                    unsigned short* __restrict__ Wb) {
    int i = (blockIdx.x * 256 + threadIdx.x) * 4;
    float4 f = *(const float4*)(W + i);
    ushort4 u;
    u.x = f2bf(f.x); u.y = f2bf(f.y); u.z = f2bf(f.z); u.w = f2bf(f.w);
    *(ushort4*)(Wb + i) = u;
}

// ---- kernel 2: fused GEMM (inline fp32->bf16 A) + tanh + ctx-dot -------
// y[m,o] = sum_k x[m,k]*W[o,k]; simsT[(nt*2+wn)][b][s] = sum_{o slice} ctx[o]*tanh(y+bias[o])
__global__ __launch_bounds__(256) void gemm_sim_kernel(
    const float* __restrict__ x, const unsigned short* __restrict__ Wb,
    const float* __restrict__ bias, const float* __restrict__ ctx,
    float* __restrict__ simsT)
{
    __shared__ __align__(16) unsigned short As[128 * 64];
    __shared__ __align__(16) unsigned short Bs[128 * 64];

    // XCD-aware swizzle: the 4 nt-blocks of one mt land adjacently on one XCD
    // so A's 4x logical re-read is served by that XCD's L2.
    const int L    = blockIdx.x;
    const int xcd  = L & 7;
    const int slot = L >> 3;
    const int nt   = slot & 3;
    const int mt   = xcd * 128 + (slot >> 2);

    const int tid  = threadIdx.x;
    const int lane = tid & 63;
    const int wave = tid >> 6;
    const int wm = wave >> 1, wn = wave & 1;
    const int l15 = lane & 15, q = lane >> 4;

    // B staging (g2l16): lane -> (row-in-8, xor-swizzled 16B chunk)
    const int srow  = lane >> 3;
    const int skoff = ((lane & 7) ^ srow) * 8;
    // A staging (manual): thread -> (row group, chunk)
    const int arow = tid >> 3;            // 0..31 (+j*32)
    const int ac   = tid & 7;             // logical 16B chunk
    const int apc  = ac ^ (arow & 7);     // physical chunk (row&7 invariant in j)

    const float*          Abase = x  + (size_t)(mt * 128) * HID;
    const unsigned short* Bbase = Wb + (size_t)(nt * 128) * HID;

    f32x4 acc[4][4] = {};

    for (int kt = 0; kt < HID / 64; ++kt) {
        const int k0 = kt * 64;
        // B: async 16B global->LDS, swizzled on the source side
        #pragma unroll
        for (int t = 0; t < 4; ++t) {
            const int c = wave * 4 + t;   // chunk of 8 rows
            g2l16(Bbase + (size_t)(c * 8 + srow) * HID + k0 + skoff, &Bs[c * 512]);
        }
        // A: fp32 load -> pk-cvt bf16 -> swizzled ds_write_b128
        #pragma unroll
        for (int j = 0; j < 4; ++j) {
            const int row = arow + j * 32;
            const float4* asrc = (const float4*)(Abase + (size_t)row * HID + k0 + ac * 8);
            float4 a0 = asrc[0];
            float4 a1 = asrc[1];
            f32x8 f = {a0.x, a0.y, a0.z, a0.w, a1.x, a1.y, a1.z, a1.w};
            bf16x8 v = __builtin_convertvector(f, bf16x8);
            *(bf16x8*)&As[row * 64 + apc * 8] = v;
        }
        __syncthreads();
        #pragma unroll
        for (int kh = 0; kh < 2; ++kh) {
            bf16x8 af[4], bfr[4];
            const int lc = kh * 4 + q;    // logical 16B chunk within row
            #pragma unroll
            for (int mi = 0; mi < 4; ++mi) {
                const int row = wm * 64 + mi * 16 + l15;
                af[mi] = *(const bf16x8*)&As[row * 64 + (lc ^ (row & 7)) * 8];
            }
            #pragma unroll
            for (int ni = 0; ni < 4; ++ni) {
                const int row = wn * 64 + ni * 16 + l15;
                bfr[ni] = *(const bf16x8*)&Bs[row * 64 + (lc ^ (row & 7)) * 8];
            }
            #pragma unroll
            for (int mi = 0; mi < 4; ++mi)
                #pragma unroll
                for (int ni = 0; ni < 4; ++ni)
                    acc[mi][ni] = __builtin_amdgcn_mfma_f32_16x16x32_bf16(
                        af[mi], bfr[ni], acc[mi][ni], 0, 0, 0);
        }
        __syncthreads();
    }

    // epilogue: ctx-weighted tanh partial over this wave's 64 cols
    float ps[16];
    #pragma unroll
    for (int mi = 0; mi < 4; ++mi)
        #pragma unroll
        for (int r = 0; r < 4; ++r) {
            float s = 0.f;
            #pragma unroll
            for (int ni = 0; ni < 4; ++ni) {
                const int o = nt * 128 + wn * 64 + ni * 16 + l15;
                s += ctx[o] * tanh_fast(acc[mi][ni][r] + bias[o]);
            }
            ps[mi * 4 + r] = s;
        }
    #pragma unroll
    for (int off = 1; off < 16; off <<= 1)
        #pragma unroll
        for (int i = 0; i < 16; ++i)
            ps[i] += __shfl_xor(ps[i], off, 64);
    if (l15 == 0) {
        float* dst = simsT + (size_t)(nt * 2 + wn) * MTOT;
        #pragma unroll
        for (int mi = 0; mi < 4; ++mi)
            #pragma unroll
            for (int r = 0; r < 4; ++r) {
                const int m = mt * 128 + wm * 64 + mi * 16 + q * 4 + r;
                dst[(m & 31) * SEQ + (m >> 5)] = ps[mi * 4 + r];  // [b][s]
            }
    }
}

// ---- kernel 3: softmax over seq, per batch (sums 8 partials) -----------
__global__ __launch_bounds__(256) void softmax_kernel(const float* __restrict__ simsT,
                                                      float* __restrict__ probsT) {
    const int b = blockIdx.x;
    const int tid = threadIdx.x;
    const int lane = tid & 63, wave = tid >> 6;
    __shared__ float red[4];

    float v[16];
    #pragma unroll
    for (int i = 0; i < 16; ++i) {
        const int s = i * 256 + tid;
        float acc = 0.f;
        #pragma unroll
        for (int p = 0; p < 8; ++p)
            acc += simsT[(size_t)p * MTOT + b * SEQ + s];
        v[i] = acc;
    }

    float mx = -INFINITY;
    #pragma unroll
    for (int i = 0; i < 16; ++i) mx = fmaxf(mx, v[i]);
    #pragma unroll
    for (int off = 32; off >= 1; off >>= 1) mx = fmaxf(mx, __shfl_xor(mx, off, 64));
    if (lane == 0) red[wave] = mx;
    __syncthreads();
    mx = fmaxf(fmaxf(red[0], red[1]), fmaxf(red[2], red[3]));
    __syncthreads();

    float sum = 0.f;
    #pragma unroll
    for (int i = 0; i < 16; ++i) { v[i] = __expf(v[i] - mx); sum += v[i]; }
    #pragma unroll
    for (int off = 32; off >= 1; off >>= 1) sum += __shfl_xor(sum, off, 64);
    if (lane == 0) red[wave] = sum;
    __syncthreads();
    const float inv = 1.0f / (red[0] + red[1] + red[2] + red[3]);

    #pragma unroll
    for (int i = 0; i < 16; ++i)
        probsT[b * SEQ + i * 256 + tid] = v[i] * inv;
}

// ---- kernel 4: weighted-sum pooling (float4, fp32 x for accuracy) ------
__global__ __launch_bounds__(128) void attend_kernel(const float* __restrict__ x,
                                                     const float* __restrict__ probsT,
                                                     float* __restrict__ out) {
    const int st  = blockIdx.x;   // 0..31 (seq tile of 128)
    const int b   = blockIdx.y;   // 0..31
    const int tid = threadIdx.x;  // 0..127 -> float4 over HID
    __shared__ float p[128];
    p[tid] = probsT[b * SEQ + st * 128 + tid];
    __syncthreads();
    f32x4 acc = {};
    const f32x4* xp = (const f32x4*)x + ((size_t)st * 128 * BATCH + b) * (HID / 4) + tid;
    #pragma unroll 8
    for (int s = 0; s < 128; ++s)
        acc += p[s] * xp[(size_t)s * (BATCH * HID / 4)];
    float* o = out + b * HID + tid * 4;
    atomicAdd(o + 0, acc[0]);
    atomicAdd(o + 1, acc[1]);
    atomicAdd(o + 2, acc[2]);
    atomicAdd(o + 3, acc[3]);
}

extern "C" void kernel_launch(void* const* d_in, const int* in_sizes, int n_in,
                              void* d_out, int out_size, void* d_ws, size_t ws_size,
                              hipStream_t stream) {
    const float* x    = (const float*)d_in[0];
    const float* W    = (const float*)d_in[1];
    const float* bias = (const float*)d_in[2];
    const float* ctx  = (const float*)d_in[3];
    float* out = (float*)d_out;

    char* w = (char*)d_ws;
    unsigned short* Wb     = (unsigned short*)w;                   // 512 KB
    float*          simsT  = (float*)(w + (512 << 10));            // 4 MB
    float*          probsT = (float*)(w + (512 << 10) + (4 << 20)); // 512 KB

    hipMemsetAsync(d_out, 0, (size_t)out_size * sizeof(float), stream);
    cvt_w_kernel<<<HID * HID / 1024, 256, 0, stream>>>(W, Wb);
    gemm_sim_kernel<<<4096, 256, 0, stream>>>(x, Wb, bias, ctx, simsT);
    softmax_kernel<<<BATCH, 256, 0, stream>>>(simsT, probsT);
    attend_kernel<<<dim3(32, 32), 128, 0, stream>>>(x, probsT, out);
}